// Round 9
// baseline (307.486 us; speedup 1.0000x reference)
//
#include <hip/hip_runtime.h>
#include <hip/hip_bf16.h>
#include <hip/hip_fp16.h>

#define SEQ    2048
#define DMODEL 2048
#define NH     16
#define NKV    4
#define HD     128
#define NTOT   3072   // DMODEL + 2*NKV*HD
#define MROWS  4096   // B*SEQ

typedef __attribute__((ext_vector_type(4))) float f32x4;
typedef __attribute__((ext_vector_type(8))) __bf16 bf16x8;
typedef __attribute__((ext_vector_type(8))) unsigned short u16x8;
typedef __attribute__((ext_vector_type(4))) unsigned short u16x4;

__device__ __forceinline__ void async_copy16(const void* g, void* l) {
  __builtin_amdgcn_global_load_lds(
      (const __attribute__((address_space(1))) void*)g,
      (__attribute__((address_space(3))) void*)l, 16, 0, 0);
}

__device__ __forceinline__ unsigned short fto16(float f) {
  __hip_bfloat16 h = __float2bfloat16(f);
  return *(unsigned short*)&h;
}

__device__ __forceinline__ float b2f(unsigned short u) {
  unsigned int t = (unsigned int)u << 16;
  float f;
  __builtin_memcpy(&f, &t, 4);
  return f;
}

#define QSCALE 0.12751791437524245f          // (1/sqrt(128)) * log2(e)
#define NEG_L2RB_64 (-0.2076205059304601f)   // -log2(10000)/64

// ---------------- prep: fake-quant + fp32->bf16 convert + rope tables --------
#define NFQ   20480        // fq: 81920 groups / 4 per block
#define NCONV 8192         // conv: 8388608 elems / 1024 per block
#define NROPE 512          // rope: 131072 entries / 256 per block
__global__ __launch_bounds__(256) void prep_kernel(const float* __restrict__ Wq,
                                                   const float* __restrict__ Wk,
                                                   const float* __restrict__ Wv,
                                                   const float* __restrict__ Wp,
                                                   const float* __restrict__ x,
                                                   unsigned short* __restrict__ Wcat,
                                                   unsigned short* __restrict__ Wpq,
                                                   unsigned short* __restrict__ xb,
                                                   float* __restrict__ CS,
                                                   float* __restrict__ SN) {
  const int bid = blockIdx.x;
  const int tid = threadIdx.x;
  if (bid < NFQ) {                     // ---- fake-quant ----
    int g = bid * 4 + (tid >> 6);
    int lane = tid & 63;
    const float* W;
    unsigned short* out;
    int blk;
    if (g < 32768)      { W = Wq; out = Wcat;                          blk = g; }
    else if (g < 40960) { W = Wk; out = Wcat + (size_t)2048 * 2048;    blk = g - 32768; }
    else if (g < 49152) { W = Wv; out = Wcat + (size_t)2560 * 2048;    blk = g - 40960; }
    else                { W = Wp; out = Wpq;                           blk = g - 49152; }
    const float* p = W + (size_t)blk * 128 + lane * 2;
    float w0 = p[0], w1 = p[1];
    float m = fmaxf(fabsf(w0), fabsf(w1));
#pragma unroll
    for (int o = 32; o; o >>= 1) m = fmaxf(m, __shfl_xor(m, o));
    float s = fmaxf(m / 31.0f, 1e-12f);
    s = __half2float(__float2half(s));      // fp16 RNE round of scale
    s = fmaxf(s, 6.103515625e-05f);         // fp16 tiny
    float q0 = rintf(fminf(fmaxf(w0 / s, -32.0f), 31.0f)) * s;
    float q1 = rintf(fminf(fmaxf(w1 / s, -32.0f), 31.0f)) * s;
    unsigned short* o16 = out + (size_t)blk * 128 + lane * 2;
    o16[0] = fto16(q0);
    o16[1] = fto16(q1);
  } else if (bid < NFQ + NCONV) {      // ---- x fp32 -> bf16 ----
    int i = ((bid - NFQ) * 256 + tid) * 4;
    float4 v = *(const float4*)(x + i);
    ushort4 o;
    o.x = fto16(v.x); o.y = fto16(v.y); o.z = fto16(v.z); o.w = fto16(v.w);
    *(ushort4*)(xb + i) = o;
  } else {                             // ---- rope cos/sin tables ----
    int idx = (bid - NFQ - NCONV) * 256 + tid;   // 0..131071
    int t = idx >> 6, l = idx & 63;
    float invf = exp2f((float)l * NEG_L2RB_64);  // 10000^(-2l/128)
    float fr = (float)t * invf;
    CS[idx] = cosf(fr);
    SN[idx] = sinf(fr);
  }
}

// ---------------- bf16 MFMA GEMM, C[m,n] = sum_k A[m,k]*B[n,k] ----------------
// R3-proven config: BK=64; rule-21 involution swizzle; XCD bijective swizzle.
// FUSED epilogues (gemm1 only; block-uniform on n0):
//   n0 >= 2560 : V -> transposed to vtb   |   n0 < 2560 : RMSNorm+RoPE -> qbuf/kbuf
#define BM 128
#define BN 128
#define BK 64
template <typename OT, bool FUSED>
__global__ __launch_bounds__(256, 3) void gemm_bt(const unsigned short* __restrict__ A,
                                                  const unsigned short* __restrict__ Bm,
                                                  OT* __restrict__ C,
                                                  unsigned short* __restrict__ vtb,
                                                  unsigned short* __restrict__ qbuf,
                                                  unsigned short* __restrict__ kbuf,
                                                  const float* __restrict__ qgain,
                                                  const float* __restrict__ CS,
                                                  const float* __restrict__ SN,
                                                  int M, int N, int K) {
  __shared__ unsigned short SH[FUSED ? 16896 : 16384];
  unsigned short* As = SH;                 // 8192 elems
  unsigned short* Bs = SH + 8192;          // 8192 elems
  const int tid = threadIdx.x;
  const int wave = tid >> 6, lane = tid & 63;
  const int quad = lane >> 4, l16 = lane & 15;

  // XCD bijective swizzle (nwg % 8 == 0 for both launches: 768, 512)
  int wg = blockIdx.y * gridDim.x + blockIdx.x;
  int nwg = gridDim.x * gridDim.y;
  int cpx = nwg >> 3;
  int swz = (wg & 7) * cpx + (wg >> 3);
  int bxs = swz % gridDim.x, bys = swz / gridDim.x;
  const int m0 = bxs * BM, n0 = bys * BN;
  const int wm = (wave >> 1) * 64, wn = (wave & 1) * 64;

  const unsigned short* Ag = A + (size_t)m0 * K;
  const unsigned short* Bg = Bm + (size_t)n0 * K;

  f32x4 acc[4][4];
#pragma unroll
  for (int i = 0; i < 4; i++)
#pragma unroll
    for (int j = 0; j < 4; j++) acc[i][j] = f32x4{0.f, 0.f, 0.f, 0.f};

  const int srow = tid >> 3;
  const int sg8 = (((lane & 7) ^ (lane >> 3))) * 8;
  const unsigned short* gA = Ag + (size_t)srow * K + sg8;
  const unsigned short* gB = Bg + (size_t)srow * K + sg8;
  unsigned short* lA = &As[wave * 512];    // wave-uniform; HW scatters lane*16B
  unsigned short* lB = &Bs[wave * 512];

  for (int k0 = 0; k0 < K; k0 += BK) {
    __syncthreads();
#pragma unroll
    for (int c = 0; c < 4; ++c) async_copy16(gA + (size_t)c * 32 * K + k0, lA + c * 2048);
#pragma unroll
    for (int c = 0; c < 4; ++c) async_copy16(gB + (size_t)c * 32 * K + k0, lB + c * 2048);
    __syncthreads();
#pragma unroll
    for (int kk = 0; kk < 2; ++kk) {
      bf16x8 af[4], bf[4];
#pragma unroll
      for (int t = 0; t < 4; t++)
        af[t] = *(const bf16x8*)&As[(wm + t * 16 + l16) * BK + ((((kk << 2) + quad) ^ (l16 & 7)) << 3)];
#pragma unroll
      for (int t = 0; t < 4; t++)
        bf[t] = *(const bf16x8*)&Bs[(wn + t * 16 + l16) * BK + ((((kk << 2) + quad) ^ (l16 & 7)) << 3)];
#pragma unroll
      for (int i = 0; i < 4; i++)
#pragma unroll
        for (int j = 0; j < 4; j++)
          acc[i][j] = __builtin_amdgcn_mfma_f32_16x16x32_bf16(af[i], bf[j], acc[i][j], 0, 0, 0);
    }
  }

  if constexpr (FUSED) {
    if (n0 >= 2560) {
      const int kvh = (n0 - 2560) >> 7;
#pragma unroll
      for (int i = 0; i < 4; i++) {
        int row0 = m0 + wm + i * 16 + quad * 4;    // 4 consecutive tokens
        int bz = row0 >> 11, s0 = row0 & 2047;     // tile never crosses bz
#pragma unroll
        for (int j = 0; j < 4; j++) {
          int d = wn + j * 16 + l16;
          u16x4 o;
#pragma unroll
          for (int r = 0; r < 4; r++) o[r] = fto16(acc[i][j][r]);
          *(u16x4*)&vtb[(size_t)((bz * NKV + kvh) * HD + d) * SEQ + s0] = o;
        }
      }
      return;
    }
    // ---- Q/K section: RMSNorm + RoPE (+gain for Q) ----
    __syncthreads();                     // all waves done reading As/Bs
#pragma unroll
    for (int i = 0; i < 4; i++) {
      int tok0 = wm + i * 16 + quad * 4;
#pragma unroll
      for (int j = 0; j < 4; j++) {
        int d = wn + j * 16 + l16;
        u16x4 w;
#pragma unroll
        for (int r = 0; r < 4; r++) w[r] = fto16(acc[i][j][r]);
        *(u16x4*)&SH[d * 132 + tok0] = w;
      }
    }
    __syncthreads();
    const bool isq = (n0 < 2048);
    const int hh = isq ? (n0 >> 7) : ((n0 - 2048) >> 7);
    const float g = isq ? qgain[hh] * QSCALE : 1.0f;
#pragma unroll 1
    for (int gr = 0; gr < 8; ++gr) {
      int tk = wave * 32 + gr * 4;
      u16x4 a = *(const u16x4*)&SH[lane * 132 + tk];
      u16x4 b = *(const u16x4*)&SH[(lane + 64) * 132 + tk];
      float x1[4], x2[4], ss[4];
#pragma unroll
      for (int r = 0; r < 4; r++) {
        x1[r] = b2f(a[r]); x2[r] = b2f(b[r]);
        ss[r] = x1[r] * x1[r] + x2[r] * x2[r];
      }
#pragma unroll
      for (int o = 32; o; o >>= 1)
#pragma unroll
        for (int r = 0; r < 4; r++) ss[r] += __shfl_xor(ss[r], o);
#pragma unroll
      for (int r = 0; r < 4; r++) {
        int gt = m0 + tk + r;
        int bz = gt >> 11, tokg = gt & 2047;
        float rn = rsqrtf(ss[r] * (1.0f / 128.0f) + 1.1920929e-07f);
        float cs = CS[tokg * 64 + lane], sn = SN[tokg * 64 + lane];
        float n1 = x1[r] * rn, n2 = x2[r] * rn;
        unsigned short* dst = isq
            ? qbuf + ((size_t)(bz * NH + hh) * SEQ + tokg) * HD
            : kbuf + ((size_t)(bz * NKV + hh) * SEQ + tokg) * HD;
        dst[lane]      = fto16((n1 * cs + n2 * sn) * g);
        dst[lane + 64] = fto16((-n1 * sn + n2 * cs) * g);
      }
    }
    return;
  }

#pragma unroll
  for (int i = 0; i < 4; i++) {
    int row_base = m0 + wm + i * 16 + quad * 4;
#pragma unroll
    for (int j = 0; j < 4; j++) {
      int col = n0 + wn + j * 16 + l16;
#pragma unroll
      for (int r = 0; r < 4; r++) {
        if constexpr (sizeof(OT) == 2)
          C[(size_t)(row_base + r) * N + col] = fto16(acc[i][j][r]);
        else
          C[(size_t)(row_base + r) * N + col] = acc[i][j][r];
      }
    }
  }
}

// ---------------- flash attention with split-K on the longest q-tiles --------
// attn duration == duration of the LONGEST block (all blocks resident at t=0);
// qt 12..15 (26..32 k-tiles) are split into 2 kpos-chunks, each emitting an
// online-softmax partial (fp32 O^T, m, l); combine_kernel merges them.
// Critical path: 32 -> 24 tiles. Core loop identical to the R3/R8 version.
// bx < 12 : single block, qt = bz-paired 0..11, writes yb directly.
// bx >= 12: idx=bx-12, qi=idx>>1 (qt=12+qi), chunk=idx&1 over [0,half)/[half,nkt).
__global__ __launch_bounds__(512, 4) void attn_kernel(const unsigned short* __restrict__ qb,
                                                      const unsigned short* __restrict__ kb,
                                                      const unsigned short* __restrict__ vtb,
                                                      unsigned short* __restrict__ yb,
                                                      float* __restrict__ Opart,
                                                      float* __restrict__ mlb) {
  __shared__ unsigned short Ks[2][64 * 128];  // 32 KB (dbuf)
  __shared__ unsigned short Vt[128 * 64];     // 16 KB
  __shared__ unsigned short Ps[8][16 * 64];   // 16 KB   -> 64 KB total

  const int bx = blockIdx.x;
  const int h = blockIdx.y;
  const int bz = blockIdx.z;
  const int tid = threadIdx.x;
  const int wave = tid >> 6, lane = tid & 63;
  const int quad = lane >> 4, l16 = lane & 15;

  int qt, k0, k1, cchunk = -1, qi = 0;
  if (bx < 12) {
    qt = bz ? bx : (11 - bx);            // bz-pairing for the singles
    k0 = 0; k1 = 2 * qt + 2;
  } else {
    int idx = bx - 12;
    qi = idx >> 1; cchunk = idx & 1;
    qt = 12 + qi;
    int nkt = 2 * qt + 2, half = nkt >> 1;
    k0 = cchunk ? half : 0;
    k1 = cchunk ? nkt : half;
  }

  const int base = qt * 128 + wave * 16;  // this wave's 16-row group
  const int kdiag = base >> 6;

  const unsigned short* qg = qb + (size_t)(bz * NH + h) * SEQ * HD;
  const unsigned short* kg = kb + (size_t)(bz * NKV + (h >> 2)) * SEQ * HD;
  const unsigned short* vg = vtb + (size_t)(bz * NKV + (h >> 2)) * HD * SEQ;
  unsigned short* psw = &Ps[wave][0];

  bf16x8 qf[4];
#pragma unroll
  for (int ds = 0; ds < 4; ++ds)
    qf[ds] = *(const bf16x8*)(qg + (size_t)(base + l16) * HD + ds * 32 + quad * 8);

  f32x4 oacc[8];
#pragma unroll
  for (int j = 0; j < 8; ++j) oacc[j] = f32x4{0.f, 0.f, 0.f, 0.f};
  float m_i = -__builtin_inff();
  float l_i = 0.f;

  const int krow0 = wave * 4 + (lane >> 4);
  const int ksrcg = (lane & 15) ^ (krow0 & 15);
  const unsigned short* kgK = kg + (size_t)krow0 * HD + ksrcg * 8;

  const int vdw = tid >> 3, vgr = tid & 7;    // 64 d/iter, 8 granules/row

  // prologue: stage K(k0) direct, prefetch V(k0) to regs
  async_copy16(kgK + (size_t)k0 * 64 * HD, &Ks[k0 & 1][wave * 512]);
  async_copy16(kgK + (size_t)(k0 * 64 + 32) * HD, &Ks[k0 & 1][4096 + wave * 512]);
  u16x8 pv[2];
#pragma unroll
  for (int i = 0; i < 2; ++i)
    pv[i] = *(const u16x8*)(vg + (size_t)(i * 64 + vdw) * SEQ + k0 * 64 + vgr * 8);

  for (int kt = k0; kt < k1; ++kt) {
    // (A) full drain + barrier: prev LDS reads done, K(kt) DMA landed, pv(kt) ready
    __syncthreads();
#pragma unroll
    for (int i = 0; i < 2; ++i) {
      int d = i * 64 + vdw;
      *(u16x8*)&Vt[d * 64 + ((vgr ^ (d & 7)) << 3)] = pv[i];
    }
    if (kt + 1 < k1) {                   // stage K(kt+1): flies across compute(kt)
      const unsigned short* s = kgK + (size_t)(kt + 1) * 64 * HD;
      async_copy16(s, &Ks[(kt + 1) & 1][wave * 512]);
      async_copy16(s + (size_t)32 * HD, &Ks[(kt + 1) & 1][4096 + wave * 512]);
    }
    __asm__ volatile("s_waitcnt lgkmcnt(0)" ::: "memory");  // my V writes visible
    __builtin_amdgcn_sched_barrier(0);
    __asm__ volatile("s_barrier" ::: "memory");  // (B) V staged; K(kt+1) in flight

    if (kt + 1 < k1) {                   // prefetch V(kt+1) into regs
#pragma unroll
      for (int i = 0; i < 2; ++i)
        pv[i] = *(const u16x8*)(vg + (size_t)(i * 64 + vdw) * SEQ + (kt + 1) * 64 + vgr * 8);
    }

    if (kt <= kdiag) {
      const unsigned short* Kc = Ks[kt & 1];
      f32x4 st[4];
#pragma unroll
      for (int mt = 0; mt < 4; ++mt) st[mt] = f32x4{0.f, 0.f, 0.f, 0.f};
      __builtin_amdgcn_s_setprio(1);
#pragma unroll
      for (int mt = 0; mt < 4; ++mt)
#pragma unroll
        for (int ds = 0; ds < 4; ++ds) {
          bf16x8 kf = *(const bf16x8*)&Kc[(mt * 16 + l16) * 128 + ((((ds << 2) + quad) ^ l16) << 3)];
          st[mt] = __builtin_amdgcn_mfma_f32_16x16x32_bf16(kf, qf[ds], st[mt], 0, 0, 0);
        }
      __builtin_amdgcn_s_setprio(0);

      const int qrow = base + l16;
      float p[4][4];
      float mx = -__builtin_inff();
      if (kt == kdiag) {                 // diagonal tile: causal mask
#pragma unroll
        for (int mt = 0; mt < 4; ++mt)
#pragma unroll
          for (int r = 0; r < 4; ++r) {
            int kp = kt * 64 + mt * 16 + quad * 4 + r;
            float v = (kp <= qrow) ? st[mt][r] : -__builtin_inff();
            p[mt][r] = v;
            mx = fmaxf(mx, v);
          }
      } else {
#pragma unroll
        for (int mt = 0; mt < 4; ++mt)
#pragma unroll
          for (int r = 0; r < 4; ++r) {
            p[mt][r] = st[mt][r];
            mx = fmaxf(mx, st[mt][r]);
          }
      }
      mx = fmaxf(mx, __shfl_xor(mx, 16));
      mx = fmaxf(mx, __shfl_xor(mx, 32));
      float mnew = (mx > m_i + 8.f) ? mx : m_i;   // defer-max THR=8
      float rs = 0.f;
#pragma unroll
      for (int mt = 0; mt < 4; ++mt)
#pragma unroll
        for (int r = 0; r < 4; ++r) {
          float e = exp2f(p[mt][r] - mnew);
          p[mt][r] = e;
          rs += e;
        }
      rs += __shfl_xor(rs, 16);
      rs += __shfl_xor(rs, 32);
      if (mnew != m_i) {                 // rescale only when deferred max moved
        float a = exp2f(m_i - mnew);
#pragma unroll
        for (int j = 0; j < 8; ++j) oacc[j] *= a;
        l_i = l_i * a + rs;
        m_i = mnew;
      } else {
        l_i += rs;
      }

#pragma unroll
      for (int mt = 0; mt < 4; ++mt) {
        u16x4 w;
#pragma unroll
        for (int r = 0; r < 4; ++r) w[r] = fto16(p[mt][r]);
        int g = mt * 2 + (quad >> 1);
        *(u16x4*)&psw[l16 * 64 + ((g ^ (l16 & 7)) << 3) + (quad & 1) * 4] = w;
      }

      __asm__ volatile("s_waitcnt lgkmcnt(0)" ::: "memory");  // own P writes -> reads

      __builtin_amdgcn_s_setprio(1);
#pragma unroll
      for (int c = 0; c < 2; ++c) {
        bf16x8 pf = *(const bf16x8*)&psw[l16 * 64 + ((((c << 2) + quad) ^ (l16 & 7)) << 3)];
#pragma unroll
        for (int mt = 0; mt < 8; ++mt) {
          bf16x8 vf = *(const bf16x8*)&Vt[(mt * 16 + l16) * 64 + ((((c << 2) + quad) ^ (l16 & 7)) << 3)];
          oacc[mt] = __builtin_amdgcn_mfma_f32_16x16x32_bf16(vf, pf, oacc[mt], 0, 0, 0);
        }
      }
      __builtin_amdgcn_s_setprio(0);
    }
  }

  if (cchunk >= 0) {
    // split epilogue: store fp32 partial O^T + (m,l); combine_kernel finishes.
    const int rloc = wave * 16 + l16;    // local q row 0..127
    float* op = Opart + ((size_t)(((cchunk * 2 + bz) * NH + h) * 4 + qi) * 128 + rloc) * 128;
#pragma unroll
    for (int mt = 0; mt < 8; ++mt)
      *(f32x4*)&op[mt * 16 + quad * 4] = oacc[mt];
    if (quad == 0) {
      float* ml = mlb + (size_t)(((cchunk * 2 + bz) * NH + h) * 4 + qi) * 256;
      ml[rloc] = m_i;
      ml[128 + rloc] = l_i;
    }
    return;
  }

  // single-block epilogue: O^T row = d = mt*16+quad*4+r, col = q = l16
  {
    float il = 1.0f / l_i;
    int qrow = base + l16;
#pragma unroll
    for (int mt = 0; mt < 8; ++mt) {
      u16x4 o;
#pragma unroll
      for (int r = 0; r < 4; ++r) o[r] = fto16(oacc[mt][r] * il);
      *(u16x4*)&yb[(size_t)(bz * SEQ + qrow) * DMODEL + h * HD + mt * 16 + quad * 4] = o;
    }
  }
}

// ---------------- split-K combine: merge 2 online-softmax partials ----------
// grid 128 = (qi 4) x (h 16) x (bz 2); 256 thr: q = tid>>1, d-half = (tid&1)*64
__global__ __launch_bounds__(256) void combine_kernel(const float* __restrict__ Opart,
                                                      const float* __restrict__ mlb,
                                                      unsigned short* __restrict__ yb) {
  const int qi = blockIdx.x & 3;
  const int h = (blockIdx.x >> 2) & 15;
  const int bz = blockIdx.x >> 6;
  const int q = threadIdx.x >> 1;
  const int dh = (threadIdx.x & 1) * 64;

  const size_t i0 = (size_t)(((0 * 2 + bz) * NH + h) * 4 + qi);
  const size_t i1 = (size_t)(((1 * 2 + bz) * NH + h) * 4 + qi);
  const float m1 = mlb[i0 * 256 + q],     l1 = mlb[i0 * 256 + 128 + q];
  const float m2 = mlb[i1 * 256 + q],     l2 = mlb[i1 * 256 + 128 + q];
  const float mm = fmaxf(m1, m2);
  float w1 = exp2f(m1 - mm), w2 = exp2f(m2 - mm);
  const float il = 1.0f / (l1 * w1 + l2 * w2);
  w1 *= il; w2 *= il;

  const float* o1 = Opart + (i0 * 128 + q) * 128;
  const float* o2 = Opart + (i1 * 128 + q) * 128;
  const int qrow = (12 + qi) * 128 + q;
  unsigned short* dst = yb + (size_t)(bz * SEQ + qrow) * DMODEL + h * HD;
#pragma unroll
  for (int d0 = 0; d0 < 64; d0 += 4) {
    f32x4 a = *(const f32x4*)&o1[dh + d0];
    f32x4 b = *(const f32x4*)&o2[dh + d0];
    u16x4 o;
#pragma unroll
    for (int r = 0; r < 4; ++r) o[r] = fto16(a[r] * w1 + b[r] * w2);
    *(u16x4*)&dst[dh + d0] = o;
  }
}

extern "C" void kernel_launch(void* const* d_in, const int* in_sizes, int n_in,
                              void* d_out, int out_size, void* d_ws, size_t ws_size,
                              hipStream_t stream) {
  (void)in_sizes; (void)n_in; (void)out_size; (void)ws_size;
  const float* x  = (const float*)d_in[0];
  const float* Wq = (const float*)d_in[1];
  const float* Wk = (const float*)d_in[2];
  const float* Wv = (const float*)d_in[3];
  const float* Wp = (const float*)d_in[4];
  const float* qg = (const float*)d_in[5];
  float* out = (float*)d_out;
  char* ws = (char*)d_ws;

  // workspace layout; yb aliases xb (x consumed by GEMM1 before attn writes y)
  unsigned short* xb   = (unsigned short*)(ws + 0);          // 16.78 MB
  unsigned short* Wcat = (unsigned short*)(ws + 16777216);   // 12.58 MB (Wq|Wk|Wv rows)
  unsigned short* Wpq  = (unsigned short*)(ws + 29360128);   // 8.39 MB
  float*          CS   = (float*)(ws + 37748736);            // 0.52 MB rope cos
  float*          SN   = (float*)(ws + 38273024);            // 0.52 MB rope sin
  float*          Opart= (float*)(ws + 38797312);            // 16.78 MB fp32 partials
  float*          mlb  = (float*)(ws + 55574528);            // 1.05 MB (m,l)
  unsigned short* qbuf = (unsigned short*)(ws + 62914560);   // 16.78 MB
  unsigned short* kbuf = (unsigned short*)(ws + 79691776);   // 4.19 MB
  unsigned short* vtb  = (unsigned short*)(ws + 83886080);   // 4.19 MB (V^T)
  unsigned short* yb   = xb;

  // prep: fq (20480 blk) + x conv (8192 blk) + rope tables (512 blk)
  prep_kernel<<<NFQ + NCONV + NROPE, 256, 0, stream>>>(Wq, Wk, Wv, Wp, x,
                                                       Wcat, Wpq, xb, CS, SN);
  // gemm1: Q,K -> norm+rope -> qbuf/kbuf; V -> transposed -> vtb (all fused)
  gemm_bt<unsigned short, true><<<dim3(32, 24), 256, 0, stream>>>(
      xb, Wcat, (unsigned short*)nullptr, vtb, qbuf, kbuf, qg, CS, SN,
      MROWS, NTOT, DMODEL);
  // attn: 12 single q-tiles + 4 longest split into 2 k-chunks each
  attn_kernel<<<dim3(20, NH, 2), 512, 0, stream>>>(qbuf, kbuf, vtb, yb, Opart, mlb);
  combine_kernel<<<128, 256, 0, stream>>>(Opart, mlb, yb);
  gemm_bt<float, false><<<dim3(32, 16), 256, 0, stream>>>(
      yb, Wpq, out, nullptr, nullptr, nullptr, nullptr, nullptr, nullptr,
      MROWS, DMODEL, DMODEL);
}